// Round 14
// baseline (159.674 us; speedup 1.0000x reference)
//
#include <hip/hip_runtime.h>
#include <hip/hip_bf16.h>

// ---------------------------------------------------------------------------
// GCN: 3 x (linear -> segment-mean -> [relu]) -> log_softmax
// R14: cache-policy pass on R13 (best, 136.9us). All single-use streams go
//      NONTEMPORAL (fag outputs, lsm fp32 output, srclist/coarse/edge/x
//      streams) so the L2 keeps the gather TABLES resident (kernel
//      boundaries don't flush L2). Only tables + weights stay temporal.
//      No layout changes (R6/R10/R12 falsified those).
// CSR build: two-level LDS counting sort (R7, no global atomics).
// NOTE: assumes n <= 65536 (problem fixes N=50000).
// ---------------------------------------------------------------------------

typedef __attribute__((ext_vector_type(8))) short short8v;
typedef __attribute__((ext_vector_type(4))) float f32x4;
typedef __attribute__((ext_vector_type(2))) float f32x2;

#define NPART 256   // coarse partitions (blocks) in PA/PA2

#if defined(__has_builtin)
#if __has_builtin(__builtin_amdgcn_cvt_pk_f32_fp8) && __has_builtin(__builtin_amdgcn_cvt_pk_fp8_f32)
#define HW_FP8 1
#endif
#endif

static __device__ __forceinline__ ushort f2bf(float f) {
    __hip_bfloat16 h = __float2bfloat16(f);   // RNE
    return *reinterpret_cast<ushort*>(&h);
}

// ------------------------------ fp8 e4m3 helpers ---------------------------
#ifndef HW_FP8
static __device__ __forceinline__ float fp8_dec1(uint b) {
    uint s = b >> 7, e = (b >> 3) & 15, m = b & 7;
    float v = e ? __uint_as_float(((e + 120u) << 23) | (m << 20))
                : (float)m * 0.001953125f;   // 2^-9
    return s ? -v : v;
}
static __device__ __forceinline__ uint fp8_enc1(float f) {
    uint s = (__float_as_uint(f) >> 31) << 7;
    float a = fabsf(f);
    if (!(a < 448.f)) a = 448.f;
    if (a < 0.015625f) {
        int q = (int)rintf(a * 512.f);
        return s | (uint)q;
    }
    int e; float m = frexpf(a, &e);
    int q = (int)rintf(m * 16.f) - 8;
    int E = e - 1;
    if (q == 8) { q = 0; ++E; }
    if (E > 8) return s | 0x7E;
    return s | (uint)((E + 7) << 3) | (uint)q;
}
#endif

static __device__ __forceinline__ f32x2 fp8x2_to_f32(ushort u) {
#ifdef HW_FP8
    return __builtin_amdgcn_cvt_pk_f32_fp8((int)(uint)u, false);
#else
    f32x2 r; r.x = fp8_dec1(u & 0xFF); r.y = fp8_dec1(u >> 8); return r;
#endif
}
static __device__ __forceinline__ float fp8_to_f32(uchar b) {
    return fp8x2_to_f32((ushort)b).x;
}
static __device__ __forceinline__ uchar f32_to_fp8(float a) {
#ifdef HW_FP8
    return (uchar)(__builtin_amdgcn_cvt_pk_fp8_f32(a, a, 0, false) & 0xFF);
#else
    return (uchar)fp8_enc1(a);
#endif
}

// ------------------- GEMM1 body (fp32 sources -> fp8 out) ------------------
static __device__ __forceinline__ void gemm1_body(
    const float* __restrict__ X, const float* __restrict__ W,
    const float* __restrict__ bias, uchar* __restrict__ Y8, int n,
    int wid, int lane) {
    int r0 = wid * 16;
    if (r0 >= n) return;
    int arow = r0 + (lane & 15);
    if (arow >= n) arow = n - 1;
    int kb = lane >> 4;
    int c  = lane & 15;

    f32x4 acc[8];
#pragma unroll
    for (int ct = 0; ct < 8; ++ct) acc[ct] = (f32x4)(0.f);

#pragma unroll
    for (int kt = 0; kt < 4; ++kt) {
        const f32x4* ap = (const f32x4*)&X[(size_t)arow * 128 + kt * 32 + kb * 8];
        f32x4 a0 = __builtin_nontemporal_load(ap);       // x streamed once
        f32x4 a1 = __builtin_nontemporal_load(ap + 1);
        union { short8v v; ushort u[8]; } av;
        av.u[0] = f2bf(a0[0]); av.u[1] = f2bf(a0[1]);
        av.u[2] = f2bf(a0[2]); av.u[3] = f2bf(a0[3]);
        av.u[4] = f2bf(a1[0]); av.u[5] = f2bf(a1[1]);
        av.u[6] = f2bf(a1[2]); av.u[7] = f2bf(a1[3]);
#pragma unroll
        for (int ct = 0; ct < 8; ++ct) {
            union { short8v v; ushort u[8]; } bv;
#pragma unroll
            for (int j = 0; j < 8; ++j)
                bv.u[j] = f2bf(W[(size_t)(kt * 32 + kb * 8 + j) * 128 + ct * 16 + c]);
            acc[ct] = __builtin_amdgcn_mfma_f32_16x16x32_bf16(av.v, bv.v, acc[ct], 0, 0, 0);
        }
    }

    int rg = lane >> 4;
#pragma unroll
    for (int ct = 0; ct < 8; ++ct) {
        float bvs = bias[ct * 16 + c];
#pragma unroll
        for (int j = 0; j < 4; ++j) {
            int r = r0 + rg * 4 + j;
            if (r < n) Y8[(size_t)r * 128 + ct * 16 + c] = f32_to_fp8(acc[ct][j] + bvs);
        }
    }
}

// -------- fused PA: coarse LDS hist (NPART blocks) | gemm1 | repack --------
__global__ __launch_bounds__(256) void fused_pa(
    const int* __restrict__ col, int* __restrict__ Gmat,
    const float* __restrict__ x, const float* __restrict__ W1,
    const float* __restrict__ b1, uchar* __restrict__ h8,
    const float* __restrict__ W2, ushort* __restrict__ Wf2,
    const float* __restrict__ W3, ushort* __restrict__ Wf3,
    int n, int E, int NBKT, int ECH, int GB) {
    __shared__ uint hist[1024];
    int b = blockIdx.x, t = threadIdx.x;
    if (b < NPART) {
        for (int i = t; i < NBKT; i += 256) hist[i] = 0;
        __syncthreads();
        int e0 = b * ECH, e1 = min(e0 + ECH, E);
        for (int e = e0 + t; e < e1; e += 256) {
            int d = __builtin_nontemporal_load(&col[e]);
            atomicAdd(&hist[d >> 6], 1u);
        }
        __syncthreads();
        for (int i = t; i < NBKT; i += 256)
            Gmat[i * NPART + b] = (int)hist[i];
        return;
    }
    b -= NPART;
    if (b < GB) {
        int wid = (b * 256 + t) >> 6;
        gemm1_body(x, W1, b1, h8, n, wid, t & 63);
        return;
    }
    b -= GB;
    // repack: W2 blocks [0,8), W3 blocks [8,12)
    const float* W; ushort* Wf; int OUT; int tid;
    if (b < 8) { W = W2; Wf = Wf2; OUT = 128; tid = b * 256 + t; }
    else       { W = W3; Wf = Wf3; OUT = 64;  tid = (b - 8) * 256 + t; }
    int CT = OUT >> 4;
    int total = 4 * CT * 64;
    if (tid >= total) return;
    int kt   = tid / (CT * 64);
    int rem  = tid % (CT * 64);
    int ct   = rem >> 6;
    int lane = rem & 63;
    int c  = lane & 15;
    int kb = lane >> 4;
    ushort tmp[8];
#pragma unroll
    for (int j = 0; j < 8; ++j)
        tmp[j] = f2bf(W[(kt * 32 + kb * 8 + j) * OUT + ct * 16 + c]);
    uint4 o;
    o.x = ((uint)tmp[1] << 16) | tmp[0];
    o.y = ((uint)tmp[3] << 16) | tmp[2];
    o.z = ((uint)tmp[5] << 16) | tmp[4];
    o.w = ((uint)tmp[7] << 16) | tmp[6];
    ((uint4*)Wf)[tid] = o;
}

// ----------------- scan of flat Gmat (M = NBKT*NPART entries) --------------
__global__ void scanA_partial(const int* __restrict__ g, int* __restrict__ bsum, int M) {
    __shared__ int lds[256];
    int i = blockIdx.x * 256 + threadIdx.x;
    int v = (i < M) ? g[i] : 0;
    lds[threadIdx.x] = v;
    __syncthreads();
    for (int s = 128; s > 0; s >>= 1) {
        if (threadIdx.x < s) lds[threadIdx.x] += lds[threadIdx.x + s];
        __syncthreads();
    }
    if (threadIdx.x == 0) bsum[blockIdx.x] = lds[0];
}

// scanA_final with inline bsum prefix: block sums bsum[0..blockIdx) itself.
__global__ void scanA_final(int* __restrict__ g, const int* __restrict__ bsum, int M) {
    __shared__ int lds[256];
    int t = threadIdx.x;
    int acc = 0;
    for (int j = t; j < blockIdx.x; j += 256) acc += bsum[j];
    lds[t] = acc;
    __syncthreads();
    for (int s = 128; s > 0; s >>= 1) {
        if (t < s) lds[t] += lds[t + s];
        __syncthreads();
    }
    int blockoff = lds[0];
    __syncthreads();
    int i = blockIdx.x * 256 + t;
    int v = (i < M) ? g[i] : 0;
    lds[t] = v;
    __syncthreads();
    for (int off = 1; off < 256; off <<= 1) {
        int u = (t >= off) ? lds[t - off] : 0;
        __syncthreads();
        lds[t] += u;
        __syncthreads();
    }
    if (i < M) g[i] = lds[t] - v + blockoff;   // exclusive
}

// ------------------- PA2: coarse scatter (LDS cursors) ---------------------
__global__ __launch_bounds__(256) void pa2_scatter(
    const int* __restrict__ row, const int* __restrict__ col,
    const int* __restrict__ Gscan, uint* __restrict__ coarse,
    int E, int NBKT, int ECH) {
    __shared__ uint cur[1024];
    int p = blockIdx.x, t = threadIdx.x;
    for (int i = t; i < NBKT; i += 256) cur[i] = (uint)Gscan[i * NPART + p];
    __syncthreads();
    int e0 = p * ECH, e1 = min(e0 + ECH, E);
    for (int e = e0 + t; e < e1; e += 256) {
        int d = __builtin_nontemporal_load(&col[e]);
        int r = __builtin_nontemporal_load(&row[e]);
        uint slot = atomicAdd(&cur[d >> 6], 1u);
        __builtin_nontemporal_store(((uint)(d & 63) << 16) | (uint)(r & 0xFFFF),
                                    &coarse[slot]);
    }
}

// ---------------- PB: per-bucket fine CSR (64 nodes/bucket) ----------------
__global__ __launch_bounds__(256) void pb_fine(
    const uint* __restrict__ coarse, const int* __restrict__ Gscan,
    int* __restrict__ cnt, int* __restrict__ start,
    ushort* __restrict__ srclist16, int n, int E, int NBKT) {
    __shared__ uint c64[64];
    int b = blockIdx.x, t = threadIdx.x;
    int lo = Gscan[b * NPART];
    int hi = (b + 1 < NBKT) ? Gscan[(b + 1) * NPART] : E;
    if (t < 64) c64[t] = 0;
    __syncthreads();
    for (int i = lo + t; i < hi; i += 256)
        atomicAdd(&c64[__builtin_nontemporal_load(&coarse[i]) >> 16], 1u);
    __syncthreads();
    if (t < 64) {
        uint v = c64[t];
        uint x = v;
#pragma unroll
        for (int off = 1; off < 64; off <<= 1) {
            uint u = __shfl_up(x, off);
            if (t >= off) x += u;
        }
        uint excl = x - v;
        int node = b * 64 + t;
        if (node < n) { cnt[node] = (int)v; start[node] = lo + (int)excl; }
        c64[t] = excl;   // becomes intra-bucket cursor
    }
    __syncthreads();
    for (int i = lo + t; i < hi; i += 256) {
        uint u  = __builtin_nontemporal_load(&coarse[i]);
        uint dl = u >> 16;
        uint slot = atomicAdd(&c64[dl], 1u);
        srclist16[lo + slot] = (ushort)u;
    }
}

// --------------- gather-mean of one node from fp8 table (128-wide) ---------
static __device__ __forceinline__ void agg_node128_f8(
    const ushort* __restrict__ h16, const ushort* __restrict__ srclist16,
    int s0, int c, int lane, float& ax, float& ay) {
    ax = 0.f; ay = 0.f;
    for (int base = 0; base < c; base += 64) {
        int m = c - base;
        if (m > 64) m = 64;
        int idx = (int)__builtin_nontemporal_load(
            &srclist16[s0 + base + (lane < m ? lane : 0)]);
        int e = 0;
        for (; e + 8 <= m; e += 8) {
            int i0 = __shfl(idx, e + 0), i1 = __shfl(idx, e + 1);
            int i2 = __shfl(idx, e + 2), i3 = __shfl(idx, e + 3);
            int i4 = __shfl(idx, e + 4), i5 = __shfl(idx, e + 5);
            int i6 = __shfl(idx, e + 6), i7 = __shfl(idx, e + 7);
            ushort u0 = h16[(size_t)i0 * 64 + lane];
            ushort u1 = h16[(size_t)i1 * 64 + lane];
            ushort u2 = h16[(size_t)i2 * 64 + lane];
            ushort u3 = h16[(size_t)i3 * 64 + lane];
            ushort u4 = h16[(size_t)i4 * 64 + lane];
            ushort u5 = h16[(size_t)i5 * 64 + lane];
            ushort u6 = h16[(size_t)i6 * 64 + lane];
            ushort u7 = h16[(size_t)i7 * 64 + lane];
            f32x2 v0 = fp8x2_to_f32(u0), v1 = fp8x2_to_f32(u1);
            f32x2 v2 = fp8x2_to_f32(u2), v3 = fp8x2_to_f32(u3);
            f32x2 v4 = fp8x2_to_f32(u4), v5 = fp8x2_to_f32(u5);
            f32x2 v6 = fp8x2_to_f32(u6), v7 = fp8x2_to_f32(u7);
            ax += ((v0.x + v1.x) + (v2.x + v3.x)) + ((v4.x + v5.x) + (v6.x + v7.x));
            ay += ((v0.y + v1.y) + (v2.y + v3.y)) + ((v4.y + v5.y) + (v6.y + v7.y));
        }
        for (; e + 4 <= m; e += 4) {
            int i0 = __shfl(idx, e + 0), i1 = __shfl(idx, e + 1);
            int i2 = __shfl(idx, e + 2), i3 = __shfl(idx, e + 3);
            f32x2 v0 = fp8x2_to_f32(h16[(size_t)i0 * 64 + lane]);
            f32x2 v1 = fp8x2_to_f32(h16[(size_t)i1 * 64 + lane]);
            f32x2 v2 = fp8x2_to_f32(h16[(size_t)i2 * 64 + lane]);
            f32x2 v3 = fp8x2_to_f32(h16[(size_t)i3 * 64 + lane]);
            ax += (v0.x + v1.x) + (v2.x + v3.x);
            ay += (v0.y + v1.y) + (v2.y + v3.y);
        }
        for (; e < m; ++e) {
            int i0 = __shfl(idx, e);
            f32x2 v0 = fp8x2_to_f32(h16[(size_t)i0 * 64 + lane]);
            ax += v0.x;
            ay += v0.y;
        }
    }
}

// ------ fused: agg(fp8 table, relu) + gemm(128 x OUT), out fp8 row-major ---
// Block = 16 nodes. 4 waves aggregate 4 nodes each into a 16x128 bf16 LDS
// tile (272B stride), then run the MFMA. Output fp8 [n][OUT], NONTEMPORAL
// (protect the gather table's L2 residency).
template <int OUT>
__global__ __launch_bounds__(256) void fused_agg_gemm_f8(
    const uchar* __restrict__ h8, const int* __restrict__ start,
    const int* __restrict__ cnt, const ushort* __restrict__ srclist16,
    const ushort* __restrict__ Wf, const float* __restrict__ bias,
    uchar* __restrict__ Y8, int n) {
    constexpr int CT  = OUT / 16;
    constexpr int CTW = CT / 4;        // col-tiles per wave (128->2, 64->1)
    __shared__ uint tile[16 * 68];
    int t = threadIdx.x;
    int wave = t >> 6, lane = t & 63;
    int base = blockIdx.x * 16;
    if (base >= n) return;
    const ushort* h16 = (const ushort*)h8;

    // ---- aggregation phase: wave aggregates rows wave*4 .. wave*4+3 ----
#pragma unroll
    for (int q = 0; q < 4; ++q) {
        int r = wave * 4 + q;
        int node = base + r;
        uint pk = 0;
        if (node < n) {
            int s0 = start[node], c = cnt[node];
            float ax, ay;
            agg_node128_f8(h16, srclist16, s0, c, lane, ax, ay);
            float rx, ry;
            if (c > 0) {
                float inv = 1.f / (float)c;
                rx = ax * inv; ry = ay * inv;
            } else {
                f32x2 v = fp8x2_to_f32(h16[(size_t)node * 64 + lane]);
                rx = v.x; ry = v.y;
            }
            rx = fmaxf(rx, 0.f); ry = fmaxf(ry, 0.f);   // relu
            pk = ((uint)f2bf(ry) << 16) | f2bf(rx);
        }
        tile[r * 68 + lane] = pk;
    }
    __syncthreads();

    // ---- gemm phase: 16x128 @ 128xOUT ----
    int ar = lane & 15;
    int kb = lane >> 4;
    f32x4 acc[CTW];
#pragma unroll
    for (int j = 0; j < CTW; ++j) acc[j] = (f32x4)(0.f);

#pragma unroll
    for (int kt = 0; kt < 4; ++kt) {
        // k-tile = 32 bf16 = 16 dwords -> kt*16; kb sub-block = 8 bf16 = 4 dwords
        uint4 a4 = *(const uint4*)&tile[ar * 68 + kt * 16 + kb * 4];
        short8v a = *(const short8v*)&a4;
#pragma unroll
        for (int j = 0; j < CTW; ++j) {
            int ct = wave * CTW + j;
            short8v b = *(const short8v*)&Wf[(size_t)((kt * CT + ct) * 64 + lane) * 8];
            acc[j] = __builtin_amdgcn_mfma_f32_16x16x32_bf16(a, b, acc[j], 0, 0, 0);
        }
    }

    int c16 = lane & 15, rg = lane >> 4;
#pragma unroll
    for (int j = 0; j < CTW; ++j) {
        int ct = wave * CTW + j;
        float bv = bias[ct * 16 + c16];
#pragma unroll
        for (int jj = 0; jj < 4; ++jj) {
            int r = base + rg * 4 + jj;
            if (r < n)
                __builtin_nontemporal_store(f32_to_fp8(acc[j][jj] + bv),
                                            &Y8[(size_t)r * OUT + ct * 16 + c16]);
        }
    }
}

// D=64 final layer from fp8 table (3.2MB, L2-fits): lane owns 1 fp8;
// fused log_softmax; fp32 output NONTEMPORAL (12.8MB write must not evict
// the resident table).
__global__ __launch_bounds__(256) void agg64_lsm_f8(
    const uchar* __restrict__ h8, const int* __restrict__ start,
    const int* __restrict__ cnt, const ushort* __restrict__ srclist16,
    float* __restrict__ out, int n) {
    int wid  = (blockIdx.x * blockDim.x + threadIdx.x) >> 6;
    int lane = threadIdx.x & 63;
    if (wid >= n) return;
    int s0 = start[wid];
    int c  = cnt[wid];
    float a = 0.f;
    for (int base = 0; base < c; base += 64) {
        int m = c - base;
        if (m > 64) m = 64;
        int idx = (int)__builtin_nontemporal_load(
            &srclist16[s0 + base + (lane < m ? lane : 0)]);
        int e = 0;
        for (; e + 8 <= m; e += 8) {
            int i0 = __shfl(idx, e + 0), i1 = __shfl(idx, e + 1);
            int i2 = __shfl(idx, e + 2), i3 = __shfl(idx, e + 3);
            int i4 = __shfl(idx, e + 4), i5 = __shfl(idx, e + 5);
            int i6 = __shfl(idx, e + 6), i7 = __shfl(idx, e + 7);
            float v0 = fp8_to_f32(h8[(size_t)i0 * 64 + lane]);
            float v1 = fp8_to_f32(h8[(size_t)i1 * 64 + lane]);
            float v2 = fp8_to_f32(h8[(size_t)i2 * 64 + lane]);
            float v3 = fp8_to_f32(h8[(size_t)i3 * 64 + lane]);
            float v4 = fp8_to_f32(h8[(size_t)i4 * 64 + lane]);
            float v5 = fp8_to_f32(h8[(size_t)i5 * 64 + lane]);
            float v6 = fp8_to_f32(h8[(size_t)i6 * 64 + lane]);
            float v7 = fp8_to_f32(h8[(size_t)i7 * 64 + lane]);
            a += ((v0 + v1) + (v2 + v3)) + ((v4 + v5) + (v6 + v7));
        }
        for (; e < m; ++e) {
            int i0 = __shfl(idx, e);
            a += fp8_to_f32(h8[(size_t)i0 * 64 + lane]);
        }
    }
    float v = (c > 0) ? a / (float)c : fp8_to_f32(h8[(size_t)wid * 64 + lane]);

    float m = v;
#pragma unroll
    for (int off = 32; off > 0; off >>= 1) m = fmaxf(m, __shfl_xor(m, off));
    float ex = __expf(v - m);
    float s = ex;
#pragma unroll
    for (int off = 32; off > 0; off >>= 1) s += __shfl_xor(s, off);
    __builtin_nontemporal_store(v - m - __logf(s), &out[(size_t)wid * 64 + lane]);
}

// ---------------------------------------------------------------------------
extern "C" void kernel_launch(void* const* d_in, const int* in_sizes, int n_in,
                              void* d_out, int out_size, void* d_ws, size_t ws_size,
                              hipStream_t stream) {
    const float* x  = (const float*)d_in[0];
    const int*   ei = (const int*)d_in[1];
    const float* W1 = (const float*)d_in[2];
    const float* b1 = (const float*)d_in[3];
    const float* W2 = (const float*)d_in[4];
    const float* b2 = (const float*)d_in[5];
    const float* W3 = (const float*)d_in[6];
    const float* b3 = (const float*)d_in[7];
    float* out = (float*)d_out;

    const int n = in_sizes[0] / 128;
    const int E = in_sizes[1] / 2;
    const int* row = ei;        // edge_index[0]
    const int* col = ei + E;    // edge_index[1]

    char* ws = (char*)d_ws;
    size_t off = 0;
    auto carve = [&](size_t bytes) {
        char* p = ws + off;
        off = (off + bytes + 255) & ~(size_t)255;
        return p;
    };
    uchar*  h8a       = (uchar*)carve((size_t)n * 128);        // gemm1 out (fp8)
    uchar*  h8b       = (uchar*)carve((size_t)n * 128);        // gemm2 out (fp8)
    uchar*  t3_8      = (uchar*)carve((size_t)n * 64);         // gemm3 out (fp8, L2-fits)
    ushort* Wf2       = (ushort*)carve(4 * 8 * 64 * 8 * 2);
    ushort* Wf3       = (ushort*)carve(4 * 4 * 64 * 8 * 2);
    const int NBKT    = (n + 63) / 64;                         // <= 1024
    int*    Gmat      = (int*)carve((size_t)NBKT * NPART * sizeof(int));
    uint*   coarse    = (uint*)carve((size_t)E * sizeof(uint));
    int*    cnt       = (int*)carve((size_t)n * sizeof(int));
    int*    start     = (int*)carve((size_t)n * sizeof(int));
    ushort* srclist16 = (ushort*)carve((size_t)E * 2);
    int*    bsum      = (int*)carve(4096);

    const int ECH   = (E + NPART - 1) / NPART;
    const int M     = NBKT * NPART;              // flat Gmat entries
    const int MB    = (M + 255) / 256;
    const int nwave = (n + 15) / 16;
    const int GB    = (nwave + 3) / 4;           // gemm1 blocks (4 waves/block)
    const int FB    = (n + 15) / 16;             // fused agg+gemm blocks (16 nodes)
    const int agrid = (n + 3) / 4;               // 1 node/wave (agg64_lsm)

    // CSR build (no global atomics) + gemm1 + weight repacks
    fused_pa<<<NPART + GB + 12, 256, 0, stream>>>(col, Gmat, x, W1, b1, h8a,
                                                  W2, Wf2, W3, Wf3,
                                                  n, E, NBKT, ECH, GB);
    scanA_partial<<<MB, 256, 0, stream>>>(Gmat, bsum, M);
    scanA_final<<<MB, 256, 0, stream>>>(Gmat, bsum, M);
    pa2_scatter<<<NPART, 256, 0, stream>>>(row, col, Gmat, coarse, E, NBKT, ECH);
    pb_fine<<<NBKT, 256, 0, stream>>>(coarse, Gmat, cnt, start, srclist16, n, E, NBKT);

    // layer boundaries fused: [agg1+gemm2]->fp8, [agg2+gemm3]->fp8, agg3+lsm
    fused_agg_gemm_f8<128><<<FB, 256, 0, stream>>>(h8a, start, cnt, srclist16,
                                                   Wf2, b2, h8b, n);
    fused_agg_gemm_f8<64><<<FB, 256, 0, stream>>>(h8b, start, cnt, srclist16,
                                                  Wf3, b3, t3_8, n);
    agg64_lsm_f8<<<agrid, 256, 0, stream>>>(t3_8, start, cnt, srclist16, out, n);
}

// Round 15
// 136.795 us; speedup vs baseline: 1.1672x; 1.1672x over previous
//
#include <hip/hip_runtime.h>
#include <hip/hip_bf16.h>

// ---------------------------------------------------------------------------
// GCN: 3 x (linear -> segment-mean -> [relu]) -> log_softmax
// R15: REVERT to R13 (best, 136.9us). R14's nontemporal pass regressed +23us:
//      the fag outputs ARE the next kernel's gather tables, and temporal
//      write-allocate was pre-warming L2 for the consumer. Fourth falsified
//      cache intervention (R6 replication, R10 spatial slice, R12 temporal
//      halving, R14 policy) -> default path is at the gather-service floor.
// Structure: two-level LDS counting-sort CSR (no global atomics) | gemm1 +
//      hist + repacks fused | [agg+gemm] fused pairs on fp8 tables | final
//      fp8 agg + log_softmax.
// NOTE: assumes n <= 65536 (problem fixes N=50000).
// ---------------------------------------------------------------------------

typedef __attribute__((ext_vector_type(8))) short short8v;
typedef __attribute__((ext_vector_type(4))) float f32x4;
typedef __attribute__((ext_vector_type(2))) float f32x2;

#define NPART 256   // coarse partitions (blocks) in PA/PA2

#if defined(__has_builtin)
#if __has_builtin(__builtin_amdgcn_cvt_pk_f32_fp8) && __has_builtin(__builtin_amdgcn_cvt_pk_fp8_f32)
#define HW_FP8 1
#endif
#endif

static __device__ __forceinline__ ushort f2bf(float f) {
    __hip_bfloat16 h = __float2bfloat16(f);   // RNE
    return *reinterpret_cast<ushort*>(&h);
}

// ------------------------------ fp8 e4m3 helpers ---------------------------
#ifndef HW_FP8
static __device__ __forceinline__ float fp8_dec1(uint b) {
    uint s = b >> 7, e = (b >> 3) & 15, m = b & 7;
    float v = e ? __uint_as_float(((e + 120u) << 23) | (m << 20))
                : (float)m * 0.001953125f;   // 2^-9
    return s ? -v : v;
}
static __device__ __forceinline__ uint fp8_enc1(float f) {
    uint s = (__float_as_uint(f) >> 31) << 7;
    float a = fabsf(f);
    if (!(a < 448.f)) a = 448.f;
    if (a < 0.015625f) {
        int q = (int)rintf(a * 512.f);
        return s | (uint)q;
    }
    int e; float m = frexpf(a, &e);
    int q = (int)rintf(m * 16.f) - 8;
    int E = e - 1;
    if (q == 8) { q = 0; ++E; }
    if (E > 8) return s | 0x7E;
    return s | (uint)((E + 7) << 3) | (uint)q;
}
#endif

static __device__ __forceinline__ f32x2 fp8x2_to_f32(ushort u) {
#ifdef HW_FP8
    return __builtin_amdgcn_cvt_pk_f32_fp8((int)(uint)u, false);
#else
    f32x2 r; r.x = fp8_dec1(u & 0xFF); r.y = fp8_dec1(u >> 8); return r;
#endif
}
static __device__ __forceinline__ float fp8_to_f32(uchar b) {
    return fp8x2_to_f32((ushort)b).x;
}
static __device__ __forceinline__ uchar f32_to_fp8(float a) {
#ifdef HW_FP8
    return (uchar)(__builtin_amdgcn_cvt_pk_fp8_f32(a, a, 0, false) & 0xFF);
#else
    return (uchar)fp8_enc1(a);
#endif
}

// ------------------- GEMM1 body (fp32 sources -> fp8 out) ------------------
static __device__ __forceinline__ void gemm1_body(
    const float* __restrict__ X, const float* __restrict__ W,
    const float* __restrict__ bias, uchar* __restrict__ Y8, int n,
    int wid, int lane) {
    int r0 = wid * 16;
    if (r0 >= n) return;
    int arow = r0 + (lane & 15);
    if (arow >= n) arow = n - 1;
    int kb = lane >> 4;
    int c  = lane & 15;

    f32x4 acc[8];
#pragma unroll
    for (int ct = 0; ct < 8; ++ct) acc[ct] = (f32x4)(0.f);

#pragma unroll
    for (int kt = 0; kt < 4; ++kt) {
        const float* ap = &X[(size_t)arow * 128 + kt * 32 + kb * 8];
        float4 a0 = *(const float4*)ap;
        float4 a1 = *(const float4*)(ap + 4);
        union { short8v v; ushort u[8]; } av;
        av.u[0] = f2bf(a0.x); av.u[1] = f2bf(a0.y);
        av.u[2] = f2bf(a0.z); av.u[3] = f2bf(a0.w);
        av.u[4] = f2bf(a1.x); av.u[5] = f2bf(a1.y);
        av.u[6] = f2bf(a1.z); av.u[7] = f2bf(a1.w);
#pragma unroll
        for (int ct = 0; ct < 8; ++ct) {
            union { short8v v; ushort u[8]; } bv;
#pragma unroll
            for (int j = 0; j < 8; ++j)
                bv.u[j] = f2bf(W[(size_t)(kt * 32 + kb * 8 + j) * 128 + ct * 16 + c]);
            acc[ct] = __builtin_amdgcn_mfma_f32_16x16x32_bf16(av.v, bv.v, acc[ct], 0, 0, 0);
        }
    }

    int rg = lane >> 4;
#pragma unroll
    for (int ct = 0; ct < 8; ++ct) {
        float bvs = bias[ct * 16 + c];
#pragma unroll
        for (int j = 0; j < 4; ++j) {
            int r = r0 + rg * 4 + j;
            if (r < n) Y8[(size_t)r * 128 + ct * 16 + c] = f32_to_fp8(acc[ct][j] + bvs);
        }
    }
}

// -------- fused PA: coarse LDS hist (NPART blocks) | gemm1 | repack --------
__global__ __launch_bounds__(256) void fused_pa(
    const int* __restrict__ col, int* __restrict__ Gmat,
    const float* __restrict__ x, const float* __restrict__ W1,
    const float* __restrict__ b1, uchar* __restrict__ h8,
    const float* __restrict__ W2, ushort* __restrict__ Wf2,
    const float* __restrict__ W3, ushort* __restrict__ Wf3,
    int n, int E, int NBKT, int ECH, int GB) {
    __shared__ uint hist[1024];
    int b = blockIdx.x, t = threadIdx.x;
    if (b < NPART) {
        for (int i = t; i < NBKT; i += 256) hist[i] = 0;
        __syncthreads();
        int e0 = b * ECH, e1 = min(e0 + ECH, E);
        for (int e = e0 + t; e < e1; e += 256)
            atomicAdd(&hist[col[e] >> 6], 1u);
        __syncthreads();
        for (int i = t; i < NBKT; i += 256)
            Gmat[i * NPART + b] = (int)hist[i];
        return;
    }
    b -= NPART;
    if (b < GB) {
        int wid = (b * 256 + t) >> 6;
        gemm1_body(x, W1, b1, h8, n, wid, t & 63);
        return;
    }
    b -= GB;
    // repack: W2 blocks [0,8), W3 blocks [8,12)
    const float* W; ushort* Wf; int OUT; int tid;
    if (b < 8) { W = W2; Wf = Wf2; OUT = 128; tid = b * 256 + t; }
    else       { W = W3; Wf = Wf3; OUT = 64;  tid = (b - 8) * 256 + t; }
    int CT = OUT >> 4;
    int total = 4 * CT * 64;
    if (tid >= total) return;
    int kt   = tid / (CT * 64);
    int rem  = tid % (CT * 64);
    int ct   = rem >> 6;
    int lane = rem & 63;
    int c  = lane & 15;
    int kb = lane >> 4;
    ushort tmp[8];
#pragma unroll
    for (int j = 0; j < 8; ++j)
        tmp[j] = f2bf(W[(kt * 32 + kb * 8 + j) * OUT + ct * 16 + c]);
    uint4 o;
    o.x = ((uint)tmp[1] << 16) | tmp[0];
    o.y = ((uint)tmp[3] << 16) | tmp[2];
    o.z = ((uint)tmp[5] << 16) | tmp[4];
    o.w = ((uint)tmp[7] << 16) | tmp[6];
    ((uint4*)Wf)[tid] = o;
}

// ----------------- scan of flat Gmat (M = NBKT*NPART entries) --------------
__global__ void scanA_partial(const int* __restrict__ g, int* __restrict__ bsum, int M) {
    __shared__ int lds[256];
    int i = blockIdx.x * 256 + threadIdx.x;
    int v = (i < M) ? g[i] : 0;
    lds[threadIdx.x] = v;
    __syncthreads();
    for (int s = 128; s > 0; s >>= 1) {
        if (threadIdx.x < s) lds[threadIdx.x] += lds[threadIdx.x + s];
        __syncthreads();
    }
    if (threadIdx.x == 0) bsum[blockIdx.x] = lds[0];
}

// scanA_final with inline bsum prefix: block sums bsum[0..blockIdx) itself.
__global__ void scanA_final(int* __restrict__ g, const int* __restrict__ bsum, int M) {
    __shared__ int lds[256];
    int t = threadIdx.x;
    int acc = 0;
    for (int j = t; j < blockIdx.x; j += 256) acc += bsum[j];
    lds[t] = acc;
    __syncthreads();
    for (int s = 128; s > 0; s >>= 1) {
        if (t < s) lds[t] += lds[t + s];
        __syncthreads();
    }
    int blockoff = lds[0];
    __syncthreads();
    int i = blockIdx.x * 256 + t;
    int v = (i < M) ? g[i] : 0;
    lds[t] = v;
    __syncthreads();
    for (int off = 1; off < 256; off <<= 1) {
        int u = (t >= off) ? lds[t - off] : 0;
        __syncthreads();
        lds[t] += u;
        __syncthreads();
    }
    if (i < M) g[i] = lds[t] - v + blockoff;   // exclusive
}

// ------------------- PA2: coarse scatter (LDS cursors) ---------------------
__global__ __launch_bounds__(256) void pa2_scatter(
    const int* __restrict__ row, const int* __restrict__ col,
    const int* __restrict__ Gscan, uint* __restrict__ coarse,
    int E, int NBKT, int ECH) {
    __shared__ uint cur[1024];
    int p = blockIdx.x, t = threadIdx.x;
    for (int i = t; i < NBKT; i += 256) cur[i] = (uint)Gscan[i * NPART + p];
    __syncthreads();
    int e0 = p * ECH, e1 = min(e0 + ECH, E);
    for (int e = e0 + t; e < e1; e += 256) {
        int d = col[e];
        uint slot = atomicAdd(&cur[d >> 6], 1u);
        coarse[slot] = ((uint)(d & 63) << 16) | (uint)(row[e] & 0xFFFF);
    }
}

// ---------------- PB: per-bucket fine CSR (64 nodes/bucket) ----------------
__global__ __launch_bounds__(256) void pb_fine(
    const uint* __restrict__ coarse, const int* __restrict__ Gscan,
    int* __restrict__ cnt, int* __restrict__ start,
    ushort* __restrict__ srclist16, int n, int E, int NBKT) {
    __shared__ uint c64[64];
    int b = blockIdx.x, t = threadIdx.x;
    int lo = Gscan[b * NPART];
    int hi = (b + 1 < NBKT) ? Gscan[(b + 1) * NPART] : E;
    if (t < 64) c64[t] = 0;
    __syncthreads();
    for (int i = lo + t; i < hi; i += 256)
        atomicAdd(&c64[coarse[i] >> 16], 1u);
    __syncthreads();
    if (t < 64) {
        uint v = c64[t];
        uint x = v;
#pragma unroll
        for (int off = 1; off < 64; off <<= 1) {
            uint u = __shfl_up(x, off);
            if (t >= off) x += u;
        }
        uint excl = x - v;
        int node = b * 64 + t;
        if (node < n) { cnt[node] = (int)v; start[node] = lo + (int)excl; }
        c64[t] = excl;   // becomes intra-bucket cursor
    }
    __syncthreads();
    for (int i = lo + t; i < hi; i += 256) {
        uint u  = coarse[i];
        uint dl = u >> 16;
        uint slot = atomicAdd(&c64[dl], 1u);
        srclist16[lo + slot] = (ushort)u;
    }
}

// --------------- gather-mean of one node from fp8 table (128-wide) ---------
static __device__ __forceinline__ void agg_node128_f8(
    const ushort* __restrict__ h16, const ushort* __restrict__ srclist16,
    int s0, int c, int lane, float& ax, float& ay) {
    ax = 0.f; ay = 0.f;
    for (int base = 0; base < c; base += 64) {
        int m = c - base;
        if (m > 64) m = 64;
        int idx = (int)srclist16[s0 + base + (lane < m ? lane : 0)];
        int e = 0;
        for (; e + 8 <= m; e += 8) {
            int i0 = __shfl(idx, e + 0), i1 = __shfl(idx, e + 1);
            int i2 = __shfl(idx, e + 2), i3 = __shfl(idx, e + 3);
            int i4 = __shfl(idx, e + 4), i5 = __shfl(idx, e + 5);
            int i6 = __shfl(idx, e + 6), i7 = __shfl(idx, e + 7);
            ushort u0 = h16[(size_t)i0 * 64 + lane];
            ushort u1 = h16[(size_t)i1 * 64 + lane];
            ushort u2 = h16[(size_t)i2 * 64 + lane];
            ushort u3 = h16[(size_t)i3 * 64 + lane];
            ushort u4 = h16[(size_t)i4 * 64 + lane];
            ushort u5 = h16[(size_t)i5 * 64 + lane];
            ushort u6 = h16[(size_t)i6 * 64 + lane];
            ushort u7 = h16[(size_t)i7 * 64 + lane];
            f32x2 v0 = fp8x2_to_f32(u0), v1 = fp8x2_to_f32(u1);
            f32x2 v2 = fp8x2_to_f32(u2), v3 = fp8x2_to_f32(u3);
            f32x2 v4 = fp8x2_to_f32(u4), v5 = fp8x2_to_f32(u5);
            f32x2 v6 = fp8x2_to_f32(u6), v7 = fp8x2_to_f32(u7);
            ax += ((v0.x + v1.x) + (v2.x + v3.x)) + ((v4.x + v5.x) + (v6.x + v7.x));
            ay += ((v0.y + v1.y) + (v2.y + v3.y)) + ((v4.y + v5.y) + (v6.y + v7.y));
        }
        for (; e + 4 <= m; e += 4) {
            int i0 = __shfl(idx, e + 0), i1 = __shfl(idx, e + 1);
            int i2 = __shfl(idx, e + 2), i3 = __shfl(idx, e + 3);
            f32x2 v0 = fp8x2_to_f32(h16[(size_t)i0 * 64 + lane]);
            f32x2 v1 = fp8x2_to_f32(h16[(size_t)i1 * 64 + lane]);
            f32x2 v2 = fp8x2_to_f32(h16[(size_t)i2 * 64 + lane]);
            f32x2 v3 = fp8x2_to_f32(h16[(size_t)i3 * 64 + lane]);
            ax += (v0.x + v1.x) + (v2.x + v3.x);
            ay += (v0.y + v1.y) + (v2.y + v3.y);
        }
        for (; e < m; ++e) {
            int i0 = __shfl(idx, e);
            f32x2 v0 = fp8x2_to_f32(h16[(size_t)i0 * 64 + lane]);
            ax += v0.x;
            ay += v0.y;
        }
    }
}

// ------ fused: agg(fp8 table, relu) + gemm(128 x OUT), out fp8 row-major ---
// Block = 16 nodes. 4 waves aggregate 4 nodes each into a 16x128 bf16 LDS
// tile (272B stride), then run the MFMA. Output always fp8 [n][OUT]
// (temporal store: it pre-warms L2 for the consumer gather).
template <int OUT>
__global__ __launch_bounds__(256) void fused_agg_gemm_f8(
    const uchar* __restrict__ h8, const int* __restrict__ start,
    const int* __restrict__ cnt, const ushort* __restrict__ srclist16,
    const ushort* __restrict__ Wf, const float* __restrict__ bias,
    uchar* __restrict__ Y8, int n) {
    constexpr int CT  = OUT / 16;
    constexpr int CTW = CT / 4;        // col-tiles per wave (128->2, 64->1)
    __shared__ uint tile[16 * 68];
    int t = threadIdx.x;
    int wave = t >> 6, lane = t & 63;
    int base = blockIdx.x * 16;
    if (base >= n) return;
    const ushort* h16 = (const ushort*)h8;

    // ---- aggregation phase: wave aggregates rows wave*4 .. wave*4+3 ----
#pragma unroll
    for (int q = 0; q < 4; ++q) {
        int r = wave * 4 + q;
        int node = base + r;
        uint pk = 0;
        if (node < n) {
            int s0 = start[node], c = cnt[node];
            float ax, ay;
            agg_node128_f8(h16, srclist16, s0, c, lane, ax, ay);
            float rx, ry;
            if (c > 0) {
                float inv = 1.f / (float)c;
                rx = ax * inv; ry = ay * inv;
            } else {
                f32x2 v = fp8x2_to_f32(h16[(size_t)node * 64 + lane]);
                rx = v.x; ry = v.y;
            }
            rx = fmaxf(rx, 0.f); ry = fmaxf(ry, 0.f);   // relu
            pk = ((uint)f2bf(ry) << 16) | f2bf(rx);
        }
        tile[r * 68 + lane] = pk;
    }
    __syncthreads();

    // ---- gemm phase: 16x128 @ 128xOUT ----
    int ar = lane & 15;
    int kb = lane >> 4;
    f32x4 acc[CTW];
#pragma unroll
    for (int j = 0; j < CTW; ++j) acc[j] = (f32x4)(0.f);

#pragma unroll
    for (int kt = 0; kt < 4; ++kt) {
        // k-tile = 32 bf16 = 16 dwords -> kt*16; kb sub-block = 8 bf16 = 4 dwords
        uint4 a4 = *(const uint4*)&tile[ar * 68 + kt * 16 + kb * 4];
        short8v a = *(const short8v*)&a4;
#pragma unroll
        for (int j = 0; j < CTW; ++j) {
            int ct = wave * CTW + j;
            short8v b = *(const short8v*)&Wf[(size_t)((kt * CT + ct) * 64 + lane) * 8];
            acc[j] = __builtin_amdgcn_mfma_f32_16x16x32_bf16(a, b, acc[j], 0, 0, 0);
        }
    }

    int c16 = lane & 15, rg = lane >> 4;
#pragma unroll
    for (int j = 0; j < CTW; ++j) {
        int ct = wave * CTW + j;
        float bv = bias[ct * 16 + c16];
#pragma unroll
        for (int jj = 0; jj < 4; ++jj) {
            int r = base + rg * 4 + jj;
            if (r < n) Y8[(size_t)r * OUT + ct * 16 + c16] = f32_to_fp8(acc[j][jj] + bv);
        }
    }
}

// D=64 final layer from fp8 table (3.2MB, L2-fits): lane owns 1 fp8;
// fused log_softmax; fp32 output.
__global__ __launch_bounds__(256) void agg64_lsm_f8(
    const uchar* __restrict__ h8, const int* __restrict__ start,
    const int* __restrict__ cnt, const ushort* __restrict__ srclist16,
    float* __restrict__ out, int n) {
    int wid  = (blockIdx.x * blockDim.x + threadIdx.x) >> 6;
    int lane = threadIdx.x & 63;
    if (wid >= n) return;
    int s0 = start[wid];
    int c  = cnt[wid];
    float a = 0.f;
    for (int base = 0; base < c; base += 64) {
        int m = c - base;
        if (m > 64) m = 64;
        int idx = (int)srclist16[s0 + base + (lane < m ? lane : 0)];
        int e = 0;
        for (; e + 8 <= m; e += 8) {
            int i0 = __shfl(idx, e + 0), i1 = __shfl(idx, e + 1);
            int i2 = __shfl(idx, e + 2), i3 = __shfl(idx, e + 3);
            int i4 = __shfl(idx, e + 4), i5 = __shfl(idx, e + 5);
            int i6 = __shfl(idx, e + 6), i7 = __shfl(idx, e + 7);
            float v0 = fp8_to_f32(h8[(size_t)i0 * 64 + lane]);
            float v1 = fp8_to_f32(h8[(size_t)i1 * 64 + lane]);
            float v2 = fp8_to_f32(h8[(size_t)i2 * 64 + lane]);
            float v3 = fp8_to_f32(h8[(size_t)i3 * 64 + lane]);
            float v4 = fp8_to_f32(h8[(size_t)i4 * 64 + lane]);
            float v5 = fp8_to_f32(h8[(size_t)i5 * 64 + lane]);
            float v6 = fp8_to_f32(h8[(size_t)i6 * 64 + lane]);
            float v7 = fp8_to_f32(h8[(size_t)i7 * 64 + lane]);
            a += ((v0 + v1) + (v2 + v3)) + ((v4 + v5) + (v6 + v7));
        }
        for (; e < m; ++e) {
            int i0 = __shfl(idx, e);
            a += fp8_to_f32(h8[(size_t)i0 * 64 + lane]);
        }
    }
    float v = (c > 0) ? a / (float)c : fp8_to_f32(h8[(size_t)wid * 64 + lane]);

    float m = v;
#pragma unroll
    for (int off = 32; off > 0; off >>= 1) m = fmaxf(m, __shfl_xor(m, off));
    float ex = __expf(v - m);
    float s = ex;
#pragma unroll
    for (int off = 32; off > 0; off >>= 1) s += __shfl_xor(s, off);
    out[(size_t)wid * 64 + lane] = v - m - __logf(s);
}

// ---------------------------------------------------------------------------
extern "C" void kernel_launch(void* const* d_in, const int* in_sizes, int n_in,
                              void* d_out, int out_size, void* d_ws, size_t ws_size,
                              hipStream_t stream) {
    const float* x  = (const float*)d_in[0];
    const int*   ei = (const int*)d_in[1];
    const float* W1 = (const float*)d_in[2];
    const float* b1 = (const float*)d_in[3];
    const float* W2 = (const float*)d_in[4];
    const float* b2 = (const float*)d_in[5];
    const float* W3 = (const float*)d_in[6];
    const float* b3 = (const float*)d_in[7];
    float* out = (float*)d_out;

    const int n = in_sizes[0] / 128;
    const int E = in_sizes[1] / 2;
    const int* row = ei;        // edge_index[0]
    const int* col = ei + E;    // edge_index[1]

    char* ws = (char*)d_ws;
    size_t off = 0;
    auto carve = [&](size_t bytes) {
        char* p = ws + off;
        off = (off + bytes + 255) & ~(size_t)255;
        return p;
    };
    uchar*  h8a       = (uchar*)carve((size_t)n * 128);        // gemm1 out (fp8)
    uchar*  h8b       = (uchar*)carve((size_t)n * 128);        // gemm2 out (fp8)
    uchar*  t3_8      = (uchar*)carve((size_t)n * 64);         // gemm3 out (fp8, L2-fits)
    ushort* Wf2       = (ushort*)carve(4 * 8 * 64 * 8 * 2);
    ushort* Wf3       = (ushort*)carve(4 * 4 * 64 * 8 * 2);
    const int NBKT    = (n + 63) / 64;                         // <= 1024
    int*    Gmat      = (int*)carve((size_t)NBKT * NPART * sizeof(int));
    uint*   coarse    = (uint*)carve((size_t)E * sizeof(uint));
    int*    cnt       = (int*)carve((size_t)n * sizeof(int));
    int*    start     = (int*)carve((size_t)n * sizeof(int));
    ushort* srclist16 = (ushort*)carve((size_t)E * 2);
    int*    bsum      = (int*)carve(4096);

    const int ECH   = (E + NPART - 1) / NPART;
    const int M     = NBKT * NPART;              // flat Gmat entries
    const int MB    = (M + 255) / 256;
    const int nwave = (n + 15) / 16;
    const int GB    = (nwave + 3) / 4;           // gemm1 blocks (4 waves/block)
    const int FB    = (n + 15) / 16;             // fused agg+gemm blocks (16 nodes)
    const int agrid = (n + 3) / 4;               // 1 node/wave (agg64_lsm)

    // CSR build (no global atomics) + gemm1 + weight repacks
    fused_pa<<<NPART + GB + 12, 256, 0, stream>>>(col, Gmat, x, W1, b1, h8a,
                                                  W2, Wf2, W3, Wf3,
                                                  n, E, NBKT, ECH, GB);
    scanA_partial<<<MB, 256, 0, stream>>>(Gmat, bsum, M);
    scanA_final<<<MB, 256, 0, stream>>>(Gmat, bsum, M);
    pa2_scatter<<<NPART, 256, 0, stream>>>(row, col, Gmat, coarse, E, NBKT, ECH);
    pb_fine<<<NBKT, 256, 0, stream>>>(coarse, Gmat, cnt, start, srclist16, n, E, NBKT);

    // layer boundaries fused: [agg1+gemm2]->fp8, [agg2+gemm3]->fp8, agg3+lsm
    fused_agg_gemm_f8<128><<<FB, 256, 0, stream>>>(h8a, start, cnt, srclist16,
                                                   Wf2, b2, h8b, n);
    fused_agg_gemm_f8<64><<<FB, 256, 0, stream>>>(h8b, start, cnt, srclist16,
                                                  Wf3, b3, t3_8, n);
    agg64_lsm_f8<<<agrid, 256, 0, stream>>>(t3_8, start, cnt, srclist16, out, n);
}